// Round 7
// baseline (45.969 us; speedup 1.0000x reference)
//
#include <hip/hip_runtime.h>
#include <hip/hip_bf16.h>
#include <hip/hip_fp8.h>

#define N_ROWS 262144
#define DIM    64
#define KCB    512

#define BLOCKS  1024
#define THREADS 512          // 8 waves; each wave 32 rows (2 cols of 16)

typedef float f32x4 __attribute__((ext_vector_type(4)));

__device__ inline float dot4(float4 a) {
    return a.x * a.x + a.y * a.y + a.z * a.z + a.w * a.w;
}
__device__ inline unsigned umin2(unsigned a, unsigned b) { return a < b ? a : b; }

// pack 8 f32 (scaled) into 8 fp8-e4m3 bytes = one long
__device__ inline unsigned pk4(float a, float b, float c, float d) {
    unsigned r;
    r  = (unsigned)__hip_fp8_e4m3(a).__x;
    r |= (unsigned)__hip_fp8_e4m3(b).__x << 8;
    r |= (unsigned)__hip_fp8_e4m3(c).__x << 16;
    r |= (unsigned)__hip_fp8_e4m3(d).__x << 24;
    return r;
}
__device__ inline long pk8(float4 f0, float4 f1, float s) {
    unsigned lo = pk4(f0.x * s, f0.y * s, f0.z * s, f0.w * s);
    unsigned hi = pk4(f1.x * s, f1.y * s, f1.z * s, f1.w * s);
    return (long)(((unsigned long)hi << 32) | (unsigned long)lo);
}

// ---- kernel 1: stage fp8 codebook + wn, argmin, gather-store, loss ---------
__global__ __launch_bounds__(THREADS, 8) void vq_main(
    const float* __restrict__ x, const float* __restrict__ cb,
    float* __restrict__ out, float* __restrict__ partials)
{
    // A = -256*w in fp8 e4m3 (8B granules, XOR-swizzled); wn = 256*(1+0.5||w||^2)
    __shared__ long   cb8_sh[KCB * 8];     // 32 KiB
    __shared__ f32x4  wn_sh4[KCB / 4];     // 2 KiB
    __shared__ float  red_sh[8];

    const int tid    = threadIdx.x;
    const int lane   = tid & 63;
    const int wave   = tid >> 6;           // 0..7
    const int lane15 = lane & 15;
    const int half   = lane >> 4;          // 0..3

    const int wrow = blockIdx.x * 256 + wave * 32;
    const float* xc0 = x + (size_t)(wrow + lane15) * DIM + half * 8;       // col0
    const float* xc1 = x + (size_t)(wrow + 16 + lane15) * DIM + half * 8;  // col1

    // ---- issue x loads (in flight during staging) --------------------------
    float4 p00 = *(const float4*)xc0,        p01 = *(const float4*)(xc0 + 4);
    float4 p02 = *(const float4*)(xc0 + 32), p03 = *(const float4*)(xc0 + 36);
    float4 p10 = *(const float4*)xc1,        p11 = *(const float4*)(xc1 + 4);
    float4 p12 = *(const float4*)(xc1 + 32), p13 = *(const float4*)(xc1 + 36);

    // ---- stage codebook f32 -> fp8(-256w) into LDS; fold in wn -------------
    #pragma unroll
    for (int it = 0; it < (KCB * 8) / THREADS; ++it) {
        const int fg = tid + it * THREADS;
        const int row = fg >> 3, g = fg & 7;
        const float* src = cb + row * DIM + g * 8;
        float4 f0 = *(const float4*)src;
        float4 f1 = *(const float4*)(src + 4);
        float sq = dot4(f0) + dot4(f1);
        sq += __shfl_xor(sq, 1);
        sq += __shfl_xor(sq, 2);
        sq += __shfl_xor(sq, 4);
        cb8_sh[row * 8 + (g ^ (row & 7))] = pk8(f0, f1, -256.0f);
        if (g == 0) ((float*)wn_sh4)[row] = 256.0f + 128.0f * sq;
    }

    // ---- convert x cols to fp8 B-frags while the barrier drains ------------
    float xn0 = dot4(p00) + dot4(p01) + dot4(p02) + dot4(p03);
    float xn1 = dot4(p10) + dot4(p11) + dot4(p12) + dot4(p13);
    long b0lo = pk8(p00, p01, 1.0f), b0hi = pk8(p02, p03, 1.0f);
    long b1lo = pk8(p10, p11, 1.0f), b1hi = pk8(p12, p13, 1.0f);
    __syncthreads();

    const int swz_lo = half ^ (lane & 7);
    const int swz_hi = (4 + half) ^ (lane & 7);
    const unsigned hb = (unsigned)(half * 4);

    unsigned u0 = 0xFFFFFFFFu, u1 = 0xFFFFFFFFu;

    #pragma unroll 8
    for (int t = 0; t < 32; ++t) {
        const int arow = t * 16 + lane15;
        long  alo = cb8_sh[arow * 8 + swz_lo];   // k = half*8..+8
        long  ahi = cb8_sh[arow * 8 + swz_hi];   // k = 32+half*8..+8
        f32x4 wnv = wn_sh4[t * 4 + half];
        const unsigned kb = (unsigned)(t * 16) | hb;

        f32x4 acc = wnv;     // acc = 256*(1+0.5||w||^2 - x.w) = 256*score > 0
        acc = __builtin_amdgcn_mfma_f32_16x16x32_fp8_fp8(alo, b0lo, acc, 0, 0, 0);
        acc = __builtin_amdgcn_mfma_f32_16x16x32_fp8_fp8(ahi, b0hi, acc, 0, 0, 0);
        unsigned p0 = (__float_as_uint(acc[0]) & 0xFFFFFE00u) | kb;
        unsigned p1 = (__float_as_uint(acc[1]) & 0xFFFFFE00u) | (kb | 1u);
        unsigned p2 = (__float_as_uint(acc[2]) & 0xFFFFFE00u) | (kb | 2u);
        unsigned p3 = (__float_as_uint(acc[3]) & 0xFFFFFE00u) | (kb | 3u);
        u0 = umin2(u0, umin2(umin2(p0, p1), umin2(p2, p3)));

        f32x4 acd = wnv;
        acd = __builtin_amdgcn_mfma_f32_16x16x32_fp8_fp8(alo, b1lo, acd, 0, 0, 0);
        acd = __builtin_amdgcn_mfma_f32_16x16x32_fp8_fp8(ahi, b1hi, acd, 0, 0, 0);
        unsigned r0 = (__float_as_uint(acd[0]) & 0xFFFFFE00u) | kb;
        unsigned r1 = (__float_as_uint(acd[1]) & 0xFFFFFE00u) | (kb | 1u);
        unsigned r2 = (__float_as_uint(acd[2]) & 0xFFFFFE00u) | (kb | 2u);
        unsigned r3 = (__float_as_uint(acd[3]) & 0xFFFFFE00u) | (kb | 3u);
        u1 = umin2(u1, umin2(umin2(r0, r1), umin2(r2, r3)));
    }

    // ---- reduce across 4 halves (same lane15 = same x-row) -----------------
    unsigned f0 = u0;
    f0 = umin2(f0, (unsigned)__shfl_xor((int)f0, 16));
    f0 = umin2(f0, (unsigned)__shfl_xor((int)f0, 32));
    unsigned f1 = u1;
    f1 = umin2(f1, (unsigned)__shfl_xor((int)f1, 16));
    f1 = umin2(f1, (unsigned)__shfl_xor((int)f1, 32));

    float xs0 = xn0;
    xs0 += __shfl_xor(xs0, 16); xs0 += __shfl_xor(xs0, 32);
    float xs1 = xn1;
    xs1 += __shfl_xor(xs1, 16); xs1 += __shfl_xor(xs1, 32);

    // packed score = 256*(1+0.5||q||^2-x.q); ||x-q||^2 = xn + pf/128 - 2
    // per lane 0.25*||x-q||^2; 4 half-lanes duplicate each row -> wave sum =
    // sum_rows ||x-q||^2 (R2-proven dedup)
    float pf0 = __uint_as_float(f0 & 0xFFFFFE00u);
    float pf1 = __uint_as_float(f1 & 0xFFFFFE00u);
    float lossAcc = 0.25f * (xs0 + pf0 * (1.0f / 128.0f) - 2.0f)
                  + 0.25f * (xs1 + pf1 * (1.0f / 128.0f) - 2.0f);

    const int bk0 = (int)(f0 & 511u);
    const int bk1 = (int)(f1 & 511u);

    // ---- coalesced gather + store: instr j writes 1KB contiguous -----------
    float* outw = out + (size_t)wrow * DIM;
    #pragma unroll
    for (int j = 0; j < 8; ++j) {
        const int srcl = (j * 4 + half) & 15;
        int bk = __shfl((j >> 2) ? bk1 : bk0, srcl);
        float4 qv = *(const float4*)(cb + (size_t)bk * DIM + (lane & 15) * 4);
        *(float4*)(outw + j * 256 + lane * 4) = qv;
    }

    // ---- loss partial ------------------------------------------------------
    #pragma unroll
    for (int off = 1; off < 64; off <<= 1) lossAcc += __shfl_xor(lossAcc, off);
    if (lane == 0) red_sh[wave] = lossAcc;
    __syncthreads();
    if (tid == 0) {
        float s = 0.f;
        #pragma unroll
        for (int w = 0; w < 8; ++w) s += red_sh[w];
        partials[blockIdx.x] = s;
    }
}

// ---- kernel 2: final loss reduction (1024 partials) ------------------------
__global__ void vq_finalize(const float* __restrict__ partials,
                            float* __restrict__ out_loss) {
    __shared__ float sh[256];
    int t = threadIdx.x;
    sh[t] = partials[t] + partials[t + 256] + partials[t + 512] + partials[t + 768];
    __syncthreads();
    #pragma unroll
    for (int s = 128; s > 0; s >>= 1) {
        if (t < s) sh[t] += sh[t + s];
        __syncthreads();
    }
    // partials = sum_rows ||x-q||^2 ; vq_loss = 1.25 * sum / (N*D)
    if (t == 0) out_loss[0] = sh[0] * (1.25f / (float)(N_ROWS * DIM));
}

extern "C" void kernel_launch(void* const* d_in, const int* in_sizes, int n_in,
                              void* d_out, int out_size, void* d_ws, size_t ws_size,
                              hipStream_t stream) {
    const float* x  = (const float*)d_in[0];
    const float* cb = (const float*)d_in[1];
    float* out      = (float*)d_out;
    float* partials = (float*)d_ws;        // BLOCKS floats

    hipLaunchKernelGGL(vq_main, dim3(BLOCKS), dim3(THREADS), 0, stream,
                       x, cb, out, partials);
    hipLaunchKernelGGL(vq_finalize, dim3(1), dim3(256), 0, stream,
                       partials, out + (size_t)N_ROWS * DIM);
}

// Round 8
// 44.795 us; speedup vs baseline: 1.0262x; 1.0262x over previous
//
#include <hip/hip_runtime.h>
#include <hip/hip_bf16.h>
#include <hip/hip_fp8.h>

#define N_ROWS 262144
#define DIM    64
#define KCB    512

#define BLOCKS  1024
#define THREADS 512          // 8 waves; each wave 32 rows (2 cols of 16)

typedef float f32x4 __attribute__((ext_vector_type(4)));

__device__ inline float dot4(float4 a) {
    return a.x * a.x + a.y * a.y + a.z * a.z + a.w * a.w;
}
__device__ inline unsigned umin2(unsigned a, unsigned b) { return a < b ? a : b; }

// pack 8 f32 (scaled) into 8 fp8-e4m3 bytes = one long
__device__ inline unsigned pk4(float a, float b, float c, float d) {
    unsigned r;
    r  = (unsigned)__hip_fp8_e4m3(a).__x;
    r |= (unsigned)__hip_fp8_e4m3(b).__x << 8;
    r |= (unsigned)__hip_fp8_e4m3(c).__x << 16;
    r |= (unsigned)__hip_fp8_e4m3(d).__x << 24;
    return r;
}
__device__ inline long pk8(float4 f0, float4 f1, float s) {
    unsigned lo = pk4(f0.x * s, f0.y * s, f0.z * s, f0.w * s);
    unsigned hi = pk4(f1.x * s, f1.y * s, f1.z * s, f1.w * s);
    return (long)(((unsigned long)hi << 32) | (unsigned long)lo);
}

// ---- kernel 1: stage fp8 codebook + wn, argmin, gather-store, loss ---------
__global__ __launch_bounds__(THREADS, 2) void vq_main(
    const float* __restrict__ x, const float* __restrict__ cb,
    float* __restrict__ out, float* __restrict__ partials)
{
    // A = -256*w, fp8 e4m3, 8B granules. Row-pair interleaved + XOR swizzle:
    // granule (r,g) lives at slot (r>>1)*16 + (r&1)*8 + (g ^ ((r>>1)&7)).
    // Each 16-lane read/write phase covers 16 distinct bank-pairs -> 0 conflicts.
    __shared__ long   cb8_sh[KCB * 8];     // 32 KiB
    __shared__ f32x4  wn_sh4[KCB / 4];     // 2 KiB: 256*(1+0.5||w||^2)
    __shared__ float  red_sh[8];

    const int tid    = threadIdx.x;
    const int lane   = tid & 63;
    const int wave   = tid >> 6;           // 0..7
    const int lane15 = lane & 15;
    const int half   = lane >> 4;          // 0..3

    const int wrow = blockIdx.x * 256 + wave * 32;
    const float* xc0 = x + (size_t)(wrow + lane15) * DIM + half * 8;       // col0
    const float* xc1 = x + (size_t)(wrow + 16 + lane15) * DIM + half * 8;  // col1

    // ---- issue x loads (in flight during staging) --------------------------
    float4 p00 = *(const float4*)xc0,        p01 = *(const float4*)(xc0 + 4);
    float4 p02 = *(const float4*)(xc0 + 32), p03 = *(const float4*)(xc0 + 36);
    float4 p10 = *(const float4*)xc1,        p11 = *(const float4*)(xc1 + 4);
    float4 p12 = *(const float4*)(xc1 + 32), p13 = *(const float4*)(xc1 + 36);

    // ---- stage codebook f32 -> fp8(-256w) into LDS; fold in wn -------------
    #pragma unroll
    for (int it = 0; it < (KCB * 8) / THREADS; ++it) {
        const int fg = tid + it * THREADS;
        const int row = fg >> 3, g = fg & 7;
        const float* src = cb + row * DIM + g * 8;
        float4 f0 = *(const float4*)src;
        float4 f1 = *(const float4*)(src + 4);
        float sq = dot4(f0) + dot4(f1);
        sq += __shfl_xor(sq, 1);
        sq += __shfl_xor(sq, 2);
        sq += __shfl_xor(sq, 4);
        const int slot = ((row >> 1) << 4) + ((row & 1) << 3)
                       + (g ^ ((row >> 1) & 7));
        cb8_sh[slot] = pk8(f0, f1, -256.0f);
        if (g == 0) ((float*)wn_sh4)[row] = 256.0f + 128.0f * sq;
    }

    // ---- convert x cols to fp8 B-frags while the barrier drains ------------
    float xn0 = dot4(p00) + dot4(p01) + dot4(p02) + dot4(p03);
    float xn1 = dot4(p10) + dot4(p11) + dot4(p12) + dot4(p13);
    long b0lo = pk8(p00, p01, 1.0f), b0hi = pk8(p02, p03, 1.0f);
    long b1lo = pk8(p10, p11, 1.0f), b1hi = pk8(p12, p13, 1.0f);
    __syncthreads();

    // per-lane read slots within each t-block of 128 longs
    const int key  = (lane15 >> 1) & 7;
    const int base = (lane15 >> 1) * 16 + (lane15 & 1) * 8;
    const int slo  = base + (half ^ key);          // dims [8*half, +8)
    const int shi  = slo ^ 4;                      // dims [32+8*half, +8)
    const unsigned hb = (unsigned)(half * 4);

    unsigned u0 = 0xFFFFFFFFu, u1 = 0xFFFFFFFFu;

    #pragma unroll 8
    for (int t = 0; t < 32; ++t) {
        long  alo = cb8_sh[t * 128 + slo];
        long  ahi = cb8_sh[t * 128 + shi];
        f32x4 wnv = wn_sh4[t * 4 + half];
        const unsigned kb = (unsigned)(t * 16) | hb;

        f32x4 acc = wnv;     // acc = 256*(1+0.5||w||^2 - x.w) = 256*score > 0
        acc = __builtin_amdgcn_mfma_f32_16x16x32_fp8_fp8(alo, b0lo, acc, 0, 0, 0);
        acc = __builtin_amdgcn_mfma_f32_16x16x32_fp8_fp8(ahi, b0hi, acc, 0, 0, 0);
        unsigned p0 = (__float_as_uint(acc[0]) & 0xFFFFFE00u) | kb;
        unsigned p1 = (__float_as_uint(acc[1]) & 0xFFFFFE00u) | (kb | 1u);
        unsigned p2 = (__float_as_uint(acc[2]) & 0xFFFFFE00u) | (kb | 2u);
        unsigned p3 = (__float_as_uint(acc[3]) & 0xFFFFFE00u) | (kb | 3u);
        u0 = umin2(u0, umin2(umin2(p0, p1), umin2(p2, p3)));

        f32x4 acd = wnv;
        acd = __builtin_amdgcn_mfma_f32_16x16x32_fp8_fp8(alo, b1lo, acd, 0, 0, 0);
        acd = __builtin_amdgcn_mfma_f32_16x16x32_fp8_fp8(ahi, b1hi, acd, 0, 0, 0);
        unsigned r0 = (__float_as_uint(acd[0]) & 0xFFFFFE00u) | kb;
        unsigned r1 = (__float_as_uint(acd[1]) & 0xFFFFFE00u) | (kb | 1u);
        unsigned r2 = (__float_as_uint(acd[2]) & 0xFFFFFE00u) | (kb | 2u);
        unsigned r3 = (__float_as_uint(acd[3]) & 0xFFFFFE00u) | (kb | 3u);
        u1 = umin2(u1, umin2(umin2(r0, r1), umin2(r2, r3)));
    }

    // ---- reduce across 4 halves (same lane15 = same x-row) -----------------
    unsigned f0 = u0;
    f0 = umin2(f0, (unsigned)__shfl_xor((int)f0, 16));
    f0 = umin2(f0, (unsigned)__shfl_xor((int)f0, 32));
    unsigned f1 = u1;
    f1 = umin2(f1, (unsigned)__shfl_xor((int)f1, 16));
    f1 = umin2(f1, (unsigned)__shfl_xor((int)f1, 32));

    float xs0 = xn0;
    xs0 += __shfl_xor(xs0, 16); xs0 += __shfl_xor(xs0, 32);
    float xs1 = xn1;
    xs1 += __shfl_xor(xs1, 16); xs1 += __shfl_xor(xs1, 32);

    // packed score = 256*(1+0.5||q||^2-x.q); ||x-q||^2 = xn + pf/128 - 2
    // per lane 0.25*||x-q||^2; 4 half-lanes duplicate each row -> wave sum =
    // sum_rows ||x-q||^2 (R2-proven dedup)
    float pf0 = __uint_as_float(f0 & 0xFFFFFE00u);
    float pf1 = __uint_as_float(f1 & 0xFFFFFE00u);
    float lossAcc = 0.25f * (xs0 + pf0 * (1.0f / 128.0f) - 2.0f)
                  + 0.25f * (xs1 + pf1 * (1.0f / 128.0f) - 2.0f);

    const int bk0 = (int)(f0 & 511u);
    const int bk1 = (int)(f1 & 511u);

    // ---- coalesced gather + store: instr j writes 1KB contiguous -----------
    float* outw = out + (size_t)wrow * DIM;
    #pragma unroll
    for (int j = 0; j < 8; ++j) {
        const int srcl = (j * 4 + half) & 15;
        int bk = __shfl((j >> 2) ? bk1 : bk0, srcl);
        float4 qv = *(const float4*)(cb + (size_t)bk * DIM + (lane & 15) * 4);
        *(float4*)(outw + j * 256 + lane * 4) = qv;
    }

    // ---- loss partial ------------------------------------------------------
    #pragma unroll
    for (int off = 1; off < 64; off <<= 1) lossAcc += __shfl_xor(lossAcc, off);
    if (lane == 0) red_sh[wave] = lossAcc;
    __syncthreads();
    if (tid == 0) {
        float s = 0.f;
        #pragma unroll
        for (int w = 0; w < 8; ++w) s += red_sh[w];
        partials[blockIdx.x] = s;
    }
}

// ---- kernel 2: final loss reduction (1024 partials) ------------------------
__global__ void vq_finalize(const float* __restrict__ partials,
                            float* __restrict__ out_loss) {
    __shared__ float sh[256];
    int t = threadIdx.x;
    sh[t] = partials[t] + partials[t + 256] + partials[t + 512] + partials[t + 768];
    __syncthreads();
    #pragma unroll
    for (int s = 128; s > 0; s >>= 1) {
        if (t < s) sh[t] += sh[t + s];
        __syncthreads();
    }
    // partials = sum_rows ||x-q||^2 ; vq_loss = 1.25 * sum / (N*D)
    if (t == 0) out_loss[0] = sh[0] * (1.25f / (float)(N_ROWS * DIM));
}

extern "C" void kernel_launch(void* const* d_in, const int* in_sizes, int n_in,
                              void* d_out, int out_size, void* d_ws, size_t ws_size,
                              hipStream_t stream) {
    const float* x  = (const float*)d_in[0];
    const float* cb = (const float*)d_in[1];
    float* out      = (float*)d_out;
    float* partials = (float*)d_ws;        // BLOCKS floats

    hipLaunchKernelGGL(vq_main, dim3(BLOCKS), dim3(THREADS), 0, stream,
                       x, cb, out, partials);
    hipLaunchKernelGGL(vq_finalize, dim3(1), dim3(256), 0, stream,
                       partials, out + (size_t)N_ROWS * DIM);
}